// Round 22
// baseline (228.386 us; speedup 1.0000x reference)
//
#include <hip/hip_runtime.h>

#define NN 100000
#define FIN 512
#define HD 16
#define CD 40
#define NE 3200000
#define EPSV 1e-5f
#define NBUK 391          // ceil(NN/256) buckets of 256 target nodes
#define CAP 9216          // slots per bucket region (mean 8192, sd ~90, 11 sigma)
#define CH 4096           // edges per partition block
#define NBLK_CNT ((NE + CH - 1) / CH)   // 782
#define NBLK_MM ((NN / 16 + 3) / 4)     // 1563
#define NSTAT 256         // k_stats blocks (deterministic reduce)
#define SMEM_BYTES 17952  // union: partition stg16K+hist1.6K | mfma 16K

typedef __attribute__((ext_vector_type(8))) short short8;
typedef __attribute__((ext_vector_type(4))) float f32x4;

static __device__ __forceinline__ short f2bf(float f) {
  union { float f; unsigned u; } a; a.f = f;
  unsigned r = a.u + 0x7fffu + ((a.u >> 16) & 1u);  // RNE to bf16
  return (short)(r >> 16);
}
static __device__ __forceinline__ float bf2f(unsigned short u) {
  union { unsigned u; float f; } a; a.u = (unsigned)u << 16; return a.f;
}
static __device__ __forceinline__ float2 bfp2f(unsigned p) {
  union { unsigned u; float f; } lo, hi;
  lo.u = p << 16;
  hi.u = p & 0xFFFF0000u;
  return make_float2(lo.f, hi.f);
}
static __device__ __forceinline__ void gload_lds(const float* g, float* l) {
  __builtin_amdgcn_global_load_lds(
      (const __attribute__((address_space(1))) void*)g,
      (__attribute__((address_space(3))) void*)l, 16, 0, 0);
}

// ---- init: bucket cursors = 0, global srcs cursor = 0 ----
__global__ void k_init(int* __restrict__ bkcur, int* __restrict__ gbase) {
  int i = threadIdx.x;
  if (i < NBUK) bkcur[i] = 0;
  if (i == 0) *gbase = 0;
}

// ---- fat kernel, role-interleaved %3: 4-phase partition (stage tgt -> hist ->
//      reserve cursor -> direct global scatter) | x@W1 MFMA (2KB-chunk async
//      LDS double-buffer).  Union LDS 17.9KB -> ~6 blocks/CU. ----
__global__ void __launch_bounds__(256) k_fat(const int* __restrict__ ei,
                                             int* __restrict__ bkcur,
                                             unsigned* __restrict__ part,
                                             const float* __restrict__ x,
                                             const float* __restrict__ W1,
                                             float* __restrict__ xw) {
  __shared__ __align__(16) char smem_u[SMEM_BYTES];
  int t = threadIdx.x;
  if (blockIdx.x % 3 == 0) {
    unsigned* stg  = (unsigned*)smem_u;         // CH staged targets (16KB)
    int*      hist = (int*)(stg + CH);          // NBUK counts, then global cursor
    int pb = blockIdx.x / 3;                    // 0..NBLK_CNT-1
    int e0 = pb * CH;
    int n = NE - e0; if (n > CH) n = CH;
    // A: zero hist, stage tgt
    for (int i = t; i < NBUK; i += 256) hist[i] = 0;
    for (int i = t; i < n; i += 256) stg[i] = (unsigned)ei[NE + e0 + i];
    __syncthreads();
    // B: histogram by bucket
    for (int i = t; i < n; i += 256) atomicAdd(&hist[stg[i] >> 8], 1);
    __syncthreads();
    // D: reserve global run; hist becomes the global slot cursor
    for (int i = t; i < NBUK; i += 256) {
      int c = hist[i];
      hist[i] = (c > 0) ? atomicAdd(&bkcur[i], c) : 0;
    }
    __syncthreads();
    // E: direct scatter to part[] at the global cursor
    for (int i = t; i < n; i += 256) {
      unsigned tg = stg[i];
      int b = tg >> 8;
      int slot = atomicAdd(&hist[b], 1);
      if (slot < CAP)
        part[(size_t)b * CAP + slot] = (unsigned)ei[e0 + i] | ((tg & 255u) << 20);
    }
  } else {
    // ---------- XW1: 2KB-chunk (K=32) wave-private async-LDS dbuf MFMA ----------
    int mb = blockIdx.x - blockIdx.x / 3 - 1;   // 0..NBLK_MM-1
    int wave = t >> 6;
    int lane = t & 63;
    int tile = mb * 4 + wave;
    int row0 = tile * 16;
    if (row0 >= NN) return;
    int lr = lane & 15;
    int kg = lane >> 4;
    float* xs = (float*)smem_u + wave * 1024;   // 2 bufs x 512 floats (4KB/wave)

    short8 bfrag[16];
#pragma unroll
    for (int s = 0; s < 16; s++) {
      int kbase = s * 32 + kg * 8;
      short8 bf;
#pragma unroll
      for (int i = 0; i < 8; i++) bf[i] = f2bf(W1[(kbase + i) * HD + lr]);
      bfrag[s] = bf;
    }

    const float* xbase = x + (size_t)row0 * FIN;
    int rr8 = lane >> 3;     // 0..7 (row within call)
    int pos = lane & 7;      // stored unit position
    // chunk c = K floats [c*32, c*32+32) of rows 0..15; row r stored at
    // 128B*r, unit u at position (u+r)&7 (bank rotation). gload_lds writes
    // linearly (base+lane*16), so the ROTATION is applied on the global src.
#define STAGE(c)                                                         \
    {                                                                    \
      float* dst = xs + ((c) & 1) * 512;                                 \
      _Pragma("unroll")                                                  \
      for (int j = 0; j < 2; j++) {                                      \
        int row = j * 8 + rr8;                                           \
        int u = (pos - row) & 7;                                         \
        gload_lds(xbase + (size_t)row * FIN + (c) * 32 + u * 4,          \
                  dst + j * 256);                                        \
      }                                                                  \
    }

    STAGE(0);
    STAGE(1);
    f32x4 acc = {0.f, 0.f, 0.f, 0.f};
#pragma unroll
    for (int s = 0; s < 16; s++) {
      if (s < 15) { asm volatile("s_waitcnt vmcnt(2)" ::: "memory"); }
      else        { asm volatile("s_waitcnt vmcnt(0)" ::: "memory"); }
      __builtin_amdgcn_sched_barrier(0);
      const float* bufp = xs + (s & 1) * 512;
      f32x4 u0 = *(const f32x4*)(bufp + lr * 32 + ((2 * kg + lr) & 7) * 4);
      f32x4 u1 = *(const f32x4*)(bufp + lr * 32 + ((2 * kg + 1 + lr) & 7) * 4);
      short8 af;
      af[0] = f2bf(u0.x); af[1] = f2bf(u0.y); af[2] = f2bf(u0.z); af[3] = f2bf(u0.w);
      af[4] = f2bf(u1.x); af[5] = f2bf(u1.y); af[6] = f2bf(u1.z); af[7] = f2bf(u1.w);
      acc = __builtin_amdgcn_mfma_f32_16x16x32_bf16(af, bfrag[s], acc, 0, 0, 0);
      __builtin_amdgcn_sched_barrier(0);
      if (s < 14) STAGE(s + 2);
    }
#undef STAGE
#pragma unroll
    for (int i = 0; i < 4; i++)
      xw[(size_t)(row0 + kg * 4 + i) * HD + lr] = acc[i];
  }
}

// ---- per bucket (1024 thr): hist -> dis/off/offe + y1(bf16) = dis*xw; LDS
//      sort srcs by local node; one fully-coalesced srcs write ----
__global__ void __launch_bounds__(1024) k_bucket(const int* __restrict__ bkcur,
                                                 const unsigned* __restrict__ part,
                                                 const float* __restrict__ xw,
                                                 int* __restrict__ gbase,
                                                 int* __restrict__ off,
                                                 int* __restrict__ offe,
                                                 float* __restrict__ dis,
                                                 unsigned short* __restrict__ y1b,
                                                 int* __restrict__ srcs) {
  __shared__ unsigned ssrc[CAP];
  __shared__ int lh[256];
  __shared__ int lb[256];
  __shared__ int base_s;
  int b = blockIdx.x, t = threadIdx.x;
  int cnt = bkcur[b]; if (cnt > CAP) cnt = CAP;
  const unsigned* bp = part + (size_t)b * CAP;
  if (t < 256) lh[t] = 0;
  __syncthreads();
  for (int i = t; i < cnt; i += 1024) atomicAdd(&lh[(bp[i] >> 20) & 255], 1);
  __syncthreads();
  int h = 0;
  if (t < 256) { h = lh[t]; lb[t] = h; }
  __syncthreads();
  for (int d = 1; d < 256; d <<= 1) {
    int u = (t < 256 && t >= d) ? lb[t - d] : 0;
    __syncthreads();
    if (t < 256) lb[t] += u;
    __syncthreads();
  }
  if (t == 255) base_s = atomicAdd(gbase, lb[255]);
  __syncthreads();
  int base = base_s;
  if (t < 256) {
    int excl = lb[t] - h;
    int node = (b << 8) + t;
    if (node < NN) {
      off[node] = base + excl;
      offe[node] = base + excl + h;
      float d = rsqrtf((float)(1 + h));
      dis[node] = d;
      const f32x4* xp = (const f32x4*)(xw + (size_t)node * HD);
      f32x4 v0 = xp[0] * d, v1 = xp[1] * d, v2 = xp[2] * d, v3 = xp[3] * d;
      short8 r0, r1;
      r0[0] = f2bf(v0.x); r0[1] = f2bf(v0.y); r0[2] = f2bf(v0.z); r0[3] = f2bf(v0.w);
      r0[4] = f2bf(v1.x); r0[5] = f2bf(v1.y); r0[6] = f2bf(v1.z); r0[7] = f2bf(v1.w);
      r1[0] = f2bf(v2.x); r1[1] = f2bf(v2.y); r1[2] = f2bf(v2.z); r1[3] = f2bf(v2.w);
      r1[4] = f2bf(v3.x); r1[5] = f2bf(v3.y); r1[6] = f2bf(v3.z); r1[7] = f2bf(v3.w);
      short8* yp = (short8*)(y1b + (size_t)node * HD);
      yp[0] = r0; yp[1] = r1;
    }
    lh[t] = excl;
  }
  __syncthreads();
  for (int i = t; i < cnt; i += 1024) {
    unsigned p = bp[i];
    int pos = atomicAdd(&lh[(p >> 20) & 255], 1);
    ssrc[pos] = p & 0xFFFFFu;
  }
  __syncthreads();
  for (int i = t; i < cnt; i += 1024) srcs[base + i] = (int)ssrc[i];
}

// ---- gather layer 1 (wave per node, 8 edge-slots x 4-deep, u32 pair loads):
//      h = relu(d*(y1[n]+sum)+b1) ----
__global__ void __launch_bounds__(256) k_g1(const int* __restrict__ off,
                                            const int* __restrict__ offe,
                                            const int* __restrict__ srcs,
                                            const float* __restrict__ dis,
                                            const unsigned short* __restrict__ y1b,
                                            const float* __restrict__ b1,
                                            float* __restrict__ h) {
  int node = (blockIdx.x * blockDim.x + threadIdx.x) >> 6;
  if (node >= NN) return;
  int lane = threadIdx.x & 63;
  int cp = lane & 7;
  int g = lane >> 3;
  int start = off[node], end = offe[node];
  const unsigned* y1u = (const unsigned*)y1b;
  float ax = 0.f, ay = 0.f;
  int i = start + g;
  for (; i + 24 < end; i += 32) {
    int r0 = srcs[i];
    int r1 = srcs[i + 8];
    int r2 = srcs[i + 16];
    int r3 = srcs[i + 24];
    float2 p0 = bfp2f(y1u[(size_t)r0 * 8 + cp]);
    float2 p1 = bfp2f(y1u[(size_t)r1 * 8 + cp]);
    float2 p2 = bfp2f(y1u[(size_t)r2 * 8 + cp]);
    float2 p3 = bfp2f(y1u[(size_t)r3 * 8 + cp]);
    ax += (p0.x + p1.x) + (p2.x + p3.x);
    ay += (p0.y + p1.y) + (p2.y + p3.y);
  }
  for (; i < end; i += 8) {
    float2 p = bfp2f(y1u[(size_t)srcs[i] * 8 + cp]);
    ax += p.x; ay += p.y;
  }
#pragma unroll
  for (int m = 8; m < 64; m <<= 1) {
    ax += __shfl_xor(ax, m);
    ay += __shfl_xor(ay, m);
  }
  if (g == 0) {
    float d = dis[node];
    float2 pn = bfp2f(y1u[(size_t)node * 8 + cp]);
    float vx = d * (pn.x + ax) + b1[2 * cp];
    float vy = d * (pn.y + ay) + b1[2 * cp + 1];
    float2* hp = (float2*)(h + (size_t)node * HD);
    hp[cp] = make_float2(fmaxf(vx, 0.f), fmaxf(vy, 0.f));
  }
}

// ---- BN stats stage 1: deterministic per-block partials ----
__global__ void __launch_bounds__(256) k_stats(const float* __restrict__ h,
                                               float* __restrict__ partial) {
  __shared__ float wsum[4][32];
  int stride = gridDim.x * blockDim.x;
  int t0 = blockIdx.x * blockDim.x + threadIdx.x;
  f32x4 s = {0.f, 0.f, 0.f, 0.f}, s2 = {0.f, 0.f, 0.f, 0.f};
  for (int t = t0; t < NN * 4; t += stride) {
    f32x4 v = ((const f32x4*)h)[t];
    s += v; s2 += v * v;
  }
#pragma unroll
  for (int m = 4; m < 64; m <<= 1) {
    s.x += __shfl_xor(s.x, m);  s.y += __shfl_xor(s.y, m);
    s.z += __shfl_xor(s.z, m);  s.w += __shfl_xor(s.w, m);
    s2.x += __shfl_xor(s2.x, m); s2.y += __shfl_xor(s2.y, m);
    s2.z += __shfl_xor(s2.z, m); s2.w += __shfl_xor(s2.w, m);
  }
  int wave = threadIdx.x >> 6, lane = threadIdx.x & 63;
  if (lane < 4) {
    int cb = lane * 4;
    wsum[wave][cb + 0] = s.x;  wsum[wave][cb + 1] = s.y;
    wsum[wave][cb + 2] = s.z;  wsum[wave][cb + 3] = s.w;
    wsum[wave][16 + cb + 0] = s2.x; wsum[wave][16 + cb + 1] = s2.y;
    wsum[wave][16 + cb + 2] = s2.z; wsum[wave][16 + cb + 3] = s2.w;
  }
  __syncthreads();
  if (threadIdx.x < 32) {
    float a = ((wsum[0][threadIdx.x] + wsum[1][threadIdx.x]) +
               (wsum[2][threadIdx.x] + wsum[3][threadIdx.x]));
    partial[blockIdx.x * 32 + threadIdx.x] = a;
  }
}

// ---- y2(bf16) = dis*(h*sc + sh), BN finalize fused (convergent barriers) ----
__global__ void __launch_bounds__(256) k_y2(const float* __restrict__ h,
                                            const float* __restrict__ partial,
                                            const float* __restrict__ gamma,
                                            const float* __restrict__ beta,
                                            const float* __restrict__ dis,
                                            unsigned short* __restrict__ y2b) {
  __shared__ float raw[32];
  __shared__ float scs[16], shs[16];
  int j = threadIdx.x;
  if (j < 32) {
    float a = 0.f;
    for (int b = 0; b < NSTAT; b++) a += partial[b * 32 + j];
    raw[j] = a;
  }
  __syncthreads();
  if (j < 16) {
    float mean = raw[j] * (1.0f / NN);
    float var = raw[16 + j] * (1.0f / NN) - mean * mean;
    float inv = rsqrtf(var + EPSV);
    float sc = gamma[j] * inv;
    scs[j] = sc;
    shs[j] = beta[j] - mean * sc;
  }
  __syncthreads();
  int node = blockIdx.x * blockDim.x + j;
  if (node >= NN) return;
  float d = dis[node];
  const f32x4* hp = (const f32x4*)(h + (size_t)node * HD);
  const f32x4* scp = (const f32x4*)scs;
  const f32x4* shp = (const f32x4*)shs;
  f32x4 v0 = (hp[0] * scp[0] + shp[0]) * d;
  f32x4 v1 = (hp[1] * scp[1] + shp[1]) * d;
  f32x4 v2 = (hp[2] * scp[2] + shp[2]) * d;
  f32x4 v3 = (hp[3] * scp[3] + shp[3]) * d;
  short8 r0, r1;
  r0[0] = f2bf(v0.x); r0[1] = f2bf(v0.y); r0[2] = f2bf(v0.z); r0[3] = f2bf(v0.w);
  r0[4] = f2bf(v1.x); r0[5] = f2bf(v1.y); r0[6] = f2bf(v1.z); r0[7] = f2bf(v1.w);
  r1[0] = f2bf(v2.x); r1[1] = f2bf(v2.y); r1[2] = f2bf(v2.z); r1[3] = f2bf(v2.w);
  r1[4] = f2bf(v3.x); r1[5] = f2bf(v3.y); r1[6] = f2bf(v3.z); r1[7] = f2bf(v3.w);
  short8* yp = (short8*)(y2b + (size_t)node * HD);
  yp[0] = r0; yp[1] = r1;
}

// ---- gather layer 2 (wave per node, 8 slots x 4-deep, u32 pair loads):
//      lane-per-class W2 + log_softmax ----
__global__ void __launch_bounds__(256) k_g2(const int* __restrict__ off,
                                            const int* __restrict__ offe,
                                            const int* __restrict__ srcs,
                                            const float* __restrict__ dis,
                                            const unsigned short* __restrict__ y2b,
                                            const float* __restrict__ W2,
                                            const float* __restrict__ b2,
                                            float* __restrict__ out) {
  int node = (blockIdx.x * blockDim.x + threadIdx.x) >> 6;
  if (node >= NN) return;
  int lane = threadIdx.x & 63;
  int cp = lane & 7;
  int g = lane >> 3;
  int start = off[node], end = offe[node];
  const unsigned* y2u = (const unsigned*)y2b;
  float ax = 0.f, ay = 0.f;
  int i = start + g;
  for (; i + 24 < end; i += 32) {
    int r0 = srcs[i];
    int r1 = srcs[i + 8];
    int r2 = srcs[i + 16];
    int r3 = srcs[i + 24];
    float2 p0 = bfp2f(y2u[(size_t)r0 * 8 + cp]);
    float2 p1 = bfp2f(y2u[(size_t)r1 * 8 + cp]);
    float2 p2 = bfp2f(y2u[(size_t)r2 * 8 + cp]);
    float2 p3 = bfp2f(y2u[(size_t)r3 * 8 + cp]);
    ax += (p0.x + p1.x) + (p2.x + p3.x);
    ay += (p0.y + p1.y) + (p2.y + p3.y);
  }
  for (; i < end; i += 8) {
    float2 p = bfp2f(y2u[(size_t)srcs[i] * 8 + cp]);
    ax += p.x; ay += p.y;
  }
#pragma unroll
  for (int m = 8; m < 64; m <<= 1) {
    ax += __shfl_xor(ax, m);
    ay += __shfl_xor(ay, m);
  }
  float d = dis[node];
  float2 pn = bfp2f(y2u[(size_t)node * 8 + cp]);
  float rx = d * (pn.x + ax);
  float ry = d * (pn.y + ay);
  int cls = lane;
  float z = (cls < CD) ? b2[cls] : 0.f;
#pragma unroll
  for (int k = 0; k < 8; k++) {
    float rkx = __shfl(rx, k);
    float rky = __shfl(ry, k);
    if (cls < CD) {
      z += rkx * W2[(2 * k) * CD + cls];
      z += rky * W2[(2 * k + 1) * CD + cls];
    }
  }
  float zz = (cls < CD) ? z : -1e30f;
#pragma unroll
  for (int m = 1; m < 64; m <<= 1) zz = fmaxf(zz, __shfl_xor(zz, m));
  float e = (cls < CD) ? __expf(z - zz) : 0.f;
#pragma unroll
  for (int m = 1; m < 64; m <<= 1) e += __shfl_xor(e, m);
  float l = __logf(e) + zz;
  if (cls < CD) out[(size_t)node * CD + cls] = z - l;
}

extern "C" void kernel_launch(void* const* d_in, const int* in_sizes, int n_in,
                              void* d_out, int out_size, void* d_ws, size_t ws_size,
                              hipStream_t stream) {
  const float* x     = (const float*)d_in[0];
  const int*   ei    = (const int*)d_in[1];
  const float* W1    = (const float*)d_in[2];
  const float* b1    = (const float*)d_in[3];
  const float* W2    = (const float*)d_in[4];
  const float* b2    = (const float*)d_in[5];
  const float* gamma = (const float*)d_in[6];
  const float* beta  = (const float*)d_in[7];
  float* out = (float*)d_out;

  float* ws = (float*)d_ws;
  float*          dis     = ws;                            // NN
  float*          partial = ws + NN;                       // NSTAT*32
  float*          xw      = partial + NSTAT * 32;          // NN*HD f32
  unsigned short* y1b     = (unsigned short*)(xw + (size_t)NN * HD);       // NN*HD bf16
  float*          h       = (float*)(y1b + (size_t)NN * HD);               // NN*HD f32
  unsigned short* y2b     = (unsigned short*)(h + (size_t)NN * HD);        // NN*HD bf16
  int*            off     = (int*)(y2b + (size_t)NN * HD); // NN
  int*            offe    = off + NN;                      // NN
  int*            srcs    = offe + NN;                     // NE
  int*            bkcur   = srcs + NE;                     // NBUK
  int*            gbase   = bkcur + NBUK;                  // 1
  unsigned*       part    = (unsigned*)(gbase + 1);        // NBUK*CAP

  const int nblk_n   = (NN + 255) / 256;
  const int nblk_gw  = (NN * 64 + 255) / 256;              // wave per node: 25000
  const int nblk_fat = NBLK_CNT + NBLK_MM;                 // 2345, %3 interleave

  k_init<<<1, 512, 0, stream>>>(bkcur, gbase);
  k_fat<<<nblk_fat, 256, 0, stream>>>(ei, bkcur, part, x, W1, xw);
  k_bucket<<<NBUK, 1024, 0, stream>>>(bkcur, part, xw, gbase, off, offe, dis, y1b, srcs);
  k_g1<<<nblk_gw, 256, 0, stream>>>(off, offe, srcs, dis, y1b, b1, h);
  k_stats<<<NSTAT, 256, 0, stream>>>(h, partial);
  k_y2<<<nblk_n, 256, 0, stream>>>(h, partial, gamma, beta, dis, y2b);
  k_g2<<<nblk_gw, 256, 0, stream>>>(off, offe, srcs, dis, y2b, W2, b2, out);
}

// Round 23
// 202.233 us; speedup vs baseline: 1.1293x; 1.1293x over previous
//
#include <hip/hip_runtime.h>

#define NN 100000
#define FIN 512
#define HD 16
#define CD 40
#define NE 3200000
#define EPSV 1e-5f
#define NBUK 391          // ceil(NN/256) buckets of 256 target nodes
#define CAP 9216          // slots per bucket region (mean 8192, sd ~90, 11 sigma)
#define CH 4096           // edges per partition block
#define NBLK_CNT ((NE + CH - 1) / CH)   // 782
#define NBLK_MM ((NN / 16 + 3) / 4)     // 1563
#define NSTAT 256         // k_stats blocks (deterministic reduce)
#define SMEM_BYTES 37504  // union: partition 37464 B | mfma 32768 B

typedef __attribute__((ext_vector_type(8))) short short8;
typedef __attribute__((ext_vector_type(4))) float f32x4;

static __device__ __forceinline__ short f2bf(float f) {
  union { float f; unsigned u; } a; a.f = f;
  unsigned r = a.u + 0x7fffu + ((a.u >> 16) & 1u);  // RNE to bf16
  return (short)(r >> 16);
}
static __device__ __forceinline__ float bf2f(unsigned short u) {
  union { unsigned u; float f; } a; a.u = (unsigned)u << 16; return a.f;
}
static __device__ __forceinline__ float2 bfp2f(unsigned p) {
  union { unsigned u; float f; } lo, hi;
  lo.u = p << 16;
  hi.u = p & 0xFFFF0000u;
  return make_float2(lo.f, hi.f);
}
static __device__ __forceinline__ void gload_lds(const float* g, float* l) {
  __builtin_amdgcn_global_load_lds(
      (const __attribute__((address_space(1))) void*)g,
      (__attribute__((address_space(3))) void*)l, 16, 0, 0);
}

// ---- init: bucket cursors = 0, global srcs cursor = 0 ----
__global__ void k_init(int* __restrict__ bkcur, int* __restrict__ gbase) {
  int i = threadIdx.x;
  if (i < NBUK) bkcur[i] = 0;
  if (i == 0) *gbase = 0;
}

// ---- fat kernel, role-interleaved %3: partition (in-LDS counting sort) |
//      x@W1 MFMA with wave-private async LDS double-buffer staging ----
__global__ void __launch_bounds__(256) k_fat(const int* __restrict__ ei,
                                             int* __restrict__ bkcur,
                                             unsigned* __restrict__ part,
                                             const float* __restrict__ x,
                                             const float* __restrict__ W1,
                                             float* __restrict__ xw) {
  __shared__ __align__(16) char smem_u[SMEM_BYTES];
  int t = threadIdx.x;
  if (blockIdx.x % 3 == 0) {
    unsigned* stg   = (unsigned*)smem_u;        // CH, staged tgts then pos->bucket map
    unsigned* spk   = stg + CH;                 // CH, bucket-sorted payload
    int*      hist  = (int*)(spk + CH);         // NBUK
    int*      lbase = hist + NBUK;              // NBUK+1
    int*      gb    = lbase + NBUK + 1;         // NBUK
    int pb = blockIdx.x / 3;
    int e0 = pb * CH;
    int n = NE - e0; if (n > CH) n = CH;
    for (int i = t; i < NBUK; i += 256) hist[i] = 0;
    for (int i = t; i < n; i += 256) stg[i] = (unsigned)ei[NE + e0 + i];
    __syncthreads();
    for (int i = t; i < n; i += 256) atomicAdd(&hist[stg[i] >> 8], 1);
    __syncthreads();
    if (t < 64) {
      int c0 = t * 7;
      int loc[7]; int s = 0;
#pragma unroll
      for (int k = 0; k < 7; k++) {
        int idx = c0 + k;
        int v = (idx < NBUK) ? hist[idx] : 0;
        loc[k] = s; s += v;
      }
      int inc = s;
#pragma unroll
      for (int m = 1; m < 64; m <<= 1) {
        int u = __shfl_up(inc, m);
        if (t >= m) inc += u;
      }
      int base0 = inc - s;
#pragma unroll
      for (int k = 0; k < 7; k++) {
        int idx = c0 + k;
        if (idx < NBUK) lbase[idx] = base0 + loc[k];
      }
      if (t == 63) lbase[NBUK] = base0 + s;
    }
    __syncthreads();
    for (int i = t; i < NBUK; i += 256) {
      int c = hist[i];
      gb[i] = (c > 0) ? atomicAdd(&bkcur[i], c) : 0;
    }
    __syncthreads();
    for (int i = t; i < NBUK; i += 256) hist[i] = lbase[i];
    __syncthreads();
    for (int i = t; i < n; i += 256) {
      unsigned tg = stg[i];
      int b = tg >> 8;
      int pos = atomicAdd(&hist[b], 1);
      spk[pos] = (unsigned)ei[e0 + i] | ((tg & 255u) << 20);
    }
    __syncthreads();
    for (int b = t; b < NBUK; b += 256) {
      int s0 = lbase[b], s1 = lbase[b + 1];
      for (int j = s0; j < s1; j++) stg[j] = (unsigned)b;
    }
    __syncthreads();
    for (int i = t; i < n; i += 256) {
      int b = (int)stg[i];
      int slot = gb[b] + (i - lbase[b]);
      if (slot < CAP) part[(size_t)b * CAP + slot] = spk[i];
    }
  } else {
    // ---------- XW1: wave-private async-LDS double-buffered MFMA ----------
    int mb = blockIdx.x - blockIdx.x / 3 - 1;   // 0..NBLK_MM-1
    int wave = t >> 6;
    int lane = t & 63;
    int tile = mb * 4 + wave;
    int row0 = tile * 16;
    if (row0 >= NN) return;
    int lr = lane & 15;
    int kg = lane >> 4;
    float* xs = (float*)smem_u + wave * 2048;   // 2 bufs x 1024 floats

    short8 bfrag[16];
#pragma unroll
    for (int s = 0; s < 16; s++) {
      int kbase = s * 32 + kg * 8;
      short8 bf;
#pragma unroll
      for (int i = 0; i < 8; i++) bf[i] = f2bf(W1[(kbase + i) * HD + lr]);
      bfrag[s] = bf;
    }

    const float* xbase = x + (size_t)row0 * FIN;
    int rr = lane >> 4;      // 0..3
    int pos = lane & 15;
#define STAGE(c)                                                         \
    {                                                                    \
      float* dst = xs + ((c) & 1) * 1024;                                \
      _Pragma("unroll")                                                  \
      for (int j = 0; j < 4; j++) {                                      \
        int row = j * 4 + rr;                                            \
        int u = (pos - row) & 15;                                        \
        gload_lds(xbase + (size_t)row * FIN + (c) * 64 + u * 4,          \
                  dst + j * 256);                                        \
      }                                                                  \
    }

    STAGE(0);
    STAGE(1);
    f32x4 acc = {0.f, 0.f, 0.f, 0.f};
#pragma unroll
    for (int c = 0; c < 8; c++) {
      if (c < 7) { asm volatile("s_waitcnt vmcnt(4)" ::: "memory"); }
      else       { asm volatile("s_waitcnt vmcnt(0)" ::: "memory"); }
      __builtin_amdgcn_sched_barrier(0);
      const float* bufp = xs + (c & 1) * 1024;
#pragma unroll
      for (int s2 = 0; s2 < 2; s2++) {
        int lu0 = s2 * 8 + 2 * kg;
        f32x4 u0 = *(const f32x4*)(bufp + lr * 64 + ((lu0 + lr) & 15) * 4);
        f32x4 u1 = *(const f32x4*)(bufp + lr * 64 + ((lu0 + 1 + lr) & 15) * 4);
        short8 af;
        af[0] = f2bf(u0.x); af[1] = f2bf(u0.y); af[2] = f2bf(u0.z); af[3] = f2bf(u0.w);
        af[4] = f2bf(u1.x); af[5] = f2bf(u1.y); af[6] = f2bf(u1.z); af[7] = f2bf(u1.w);
        acc = __builtin_amdgcn_mfma_f32_16x16x32_bf16(af, bfrag[c * 2 + s2], acc, 0, 0, 0);
      }
      __builtin_amdgcn_sched_barrier(0);
      if (c < 6) STAGE(c + 2);
    }
#undef STAGE
#pragma unroll
    for (int i = 0; i < 4; i++)
      xw[(size_t)(row0 + kg * 4 + i) * HD + lr] = acc[i];
  }
}

// ---- per bucket (1024 thr): hist -> dis/off/offe + y1(bf16) = dis*xw; LDS
//      sort srcs by local node; one fully-coalesced srcs write ----
__global__ void __launch_bounds__(1024) k_bucket(const int* __restrict__ bkcur,
                                                 const unsigned* __restrict__ part,
                                                 const float* __restrict__ xw,
                                                 int* __restrict__ gbase,
                                                 int* __restrict__ off,
                                                 int* __restrict__ offe,
                                                 float* __restrict__ dis,
                                                 unsigned short* __restrict__ y1b,
                                                 int* __restrict__ srcs) {
  __shared__ unsigned ssrc[CAP];
  __shared__ int lh[256];
  __shared__ int lb[256];
  __shared__ int base_s;
  int b = blockIdx.x, t = threadIdx.x;
  int cnt = bkcur[b]; if (cnt > CAP) cnt = CAP;
  const unsigned* bp = part + (size_t)b * CAP;
  if (t < 256) lh[t] = 0;
  __syncthreads();
  for (int i = t; i < cnt; i += 1024) atomicAdd(&lh[(bp[i] >> 20) & 255], 1);
  __syncthreads();
  int h = 0;
  if (t < 256) { h = lh[t]; lb[t] = h; }
  __syncthreads();
  for (int d = 1; d < 256; d <<= 1) {
    int u = (t < 256 && t >= d) ? lb[t - d] : 0;
    __syncthreads();
    if (t < 256) lb[t] += u;
    __syncthreads();
  }
  if (t == 255) base_s = atomicAdd(gbase, lb[255]);
  __syncthreads();
  int base = base_s;
  if (t < 256) {
    int excl = lb[t] - h;
    int node = (b << 8) + t;
    if (node < NN) {
      off[node] = base + excl;
      offe[node] = base + excl + h;
      float d = rsqrtf((float)(1 + h));
      dis[node] = d;
      const f32x4* xp = (const f32x4*)(xw + (size_t)node * HD);
      f32x4 v0 = xp[0] * d, v1 = xp[1] * d, v2 = xp[2] * d, v3 = xp[3] * d;
      short8 r0, r1;
      r0[0] = f2bf(v0.x); r0[1] = f2bf(v0.y); r0[2] = f2bf(v0.z); r0[3] = f2bf(v0.w);
      r0[4] = f2bf(v1.x); r0[5] = f2bf(v1.y); r0[6] = f2bf(v1.z); r0[7] = f2bf(v1.w);
      r1[0] = f2bf(v2.x); r1[1] = f2bf(v2.y); r1[2] = f2bf(v2.z); r1[3] = f2bf(v2.w);
      r1[4] = f2bf(v3.x); r1[5] = f2bf(v3.y); r1[6] = f2bf(v3.z); r1[7] = f2bf(v3.w);
      short8* yp = (short8*)(y1b + (size_t)node * HD);
      yp[0] = r0; yp[1] = r1;
    }
    lh[t] = excl;
  }
  __syncthreads();
  for (int i = t; i < cnt; i += 1024) {
    unsigned p = bp[i];
    int pos = atomicAdd(&lh[(p >> 20) & 255], 1);
    ssrc[pos] = p & 0xFFFFFu;
  }
  __syncthreads();
  for (int i = t; i < cnt; i += 1024) srcs[base + i] = (int)ssrc[i];
}

// ---- gather layer 1 (wave per node, 16 edge-slots x 4-deep, uint2 loads,
//      4 channels/lane): h = relu(d*(y1[n]+sum)+b1) ----
__global__ void __launch_bounds__(256) k_g1(const int* __restrict__ off,
                                            const int* __restrict__ offe,
                                            const int* __restrict__ srcs,
                                            const float* __restrict__ dis,
                                            const unsigned short* __restrict__ y1b,
                                            const float* __restrict__ b1,
                                            float* __restrict__ h) {
  int node = (blockIdx.x * blockDim.x + threadIdx.x) >> 6;
  if (node >= NN) return;
  int lane = threadIdx.x & 63;
  int cp = lane & 3;           // channel quad -> channels 4cp..4cp+3
  int g = lane >> 2;           // edge slot 0..15
  int start = off[node], end = offe[node];
  const uint2* y1q = (const uint2*)y1b;  // 4 uint2 per row
  float a0 = 0.f, a1 = 0.f, a2 = 0.f, a3 = 0.f;
  int i = start + g;
  for (; i + 48 < end; i += 64) {
    int r0 = srcs[i];
    int r1 = srcs[i + 16];
    int r2 = srcs[i + 32];
    int r3 = srcs[i + 48];
    uint2 q0 = y1q[(size_t)r0 * 4 + cp];
    uint2 q1 = y1q[(size_t)r1 * 4 + cp];
    uint2 q2 = y1q[(size_t)r2 * 4 + cp];
    uint2 q3 = y1q[(size_t)r3 * 4 + cp];
    float2 pa, pb;
    pa = bfp2f(q0.x); pb = bfp2f(q0.y); a0 += pa.x; a1 += pa.y; a2 += pb.x; a3 += pb.y;
    pa = bfp2f(q1.x); pb = bfp2f(q1.y); a0 += pa.x; a1 += pa.y; a2 += pb.x; a3 += pb.y;
    pa = bfp2f(q2.x); pb = bfp2f(q2.y); a0 += pa.x; a1 += pa.y; a2 += pb.x; a3 += pb.y;
    pa = bfp2f(q3.x); pb = bfp2f(q3.y); a0 += pa.x; a1 += pa.y; a2 += pb.x; a3 += pb.y;
  }
  for (; i < end; i += 16) {
    uint2 q = y1q[(size_t)srcs[i] * 4 + cp];
    float2 pa = bfp2f(q.x), pb = bfp2f(q.y);
    a0 += pa.x; a1 += pa.y; a2 += pb.x; a3 += pb.y;
  }
#pragma unroll
  for (int m = 4; m < 64; m <<= 1) {
    a0 += __shfl_xor(a0, m);
    a1 += __shfl_xor(a1, m);
    a2 += __shfl_xor(a2, m);
    a3 += __shfl_xor(a3, m);
  }
  if (g == 0) {
    float d = dis[node];
    uint2 qn = y1q[(size_t)node * 4 + cp];
    float2 pa = bfp2f(qn.x), pb = bfp2f(qn.y);
    const f32x4* b1p = (const f32x4*)b1;
    f32x4 bb = b1p[cp];
    f32x4 v;
    v.x = fmaxf(d * (pa.x + a0) + bb.x, 0.f);
    v.y = fmaxf(d * (pa.y + a1) + bb.y, 0.f);
    v.z = fmaxf(d * (pb.x + a2) + bb.z, 0.f);
    v.w = fmaxf(d * (pb.y + a3) + bb.w, 0.f);
    ((f32x4*)(h + (size_t)node * HD))[cp] = v;
  }
}

// ---- BN stats stage 1: deterministic per-block partials ----
__global__ void __launch_bounds__(256) k_stats(const float* __restrict__ h,
                                               float* __restrict__ partial) {
  __shared__ float wsum[4][32];
  int stride = gridDim.x * blockDim.x;
  int t0 = blockIdx.x * blockDim.x + threadIdx.x;
  f32x4 s = {0.f, 0.f, 0.f, 0.f}, s2 = {0.f, 0.f, 0.f, 0.f};
  for (int t = t0; t < NN * 4; t += stride) {
    f32x4 v = ((const f32x4*)h)[t];
    s += v; s2 += v * v;
  }
#pragma unroll
  for (int m = 4; m < 64; m <<= 1) {
    s.x += __shfl_xor(s.x, m);  s.y += __shfl_xor(s.y, m);
    s.z += __shfl_xor(s.z, m);  s.w += __shfl_xor(s.w, m);
    s2.x += __shfl_xor(s2.x, m); s2.y += __shfl_xor(s2.y, m);
    s2.z += __shfl_xor(s2.z, m); s2.w += __shfl_xor(s2.w, m);
  }
  int wave = threadIdx.x >> 6, lane = threadIdx.x & 63;
  if (lane < 4) {
    int cb = lane * 4;
    wsum[wave][cb + 0] = s.x;  wsum[wave][cb + 1] = s.y;
    wsum[wave][cb + 2] = s.z;  wsum[wave][cb + 3] = s.w;
    wsum[wave][16 + cb + 0] = s2.x; wsum[wave][16 + cb + 1] = s2.y;
    wsum[wave][16 + cb + 2] = s2.z; wsum[wave][16 + cb + 3] = s2.w;
  }
  __syncthreads();
  if (threadIdx.x < 32) {
    float a = ((wsum[0][threadIdx.x] + wsum[1][threadIdx.x]) +
               (wsum[2][threadIdx.x] + wsum[3][threadIdx.x]));
    partial[blockIdx.x * 32 + threadIdx.x] = a;
  }
}

// ---- y2(bf16) = dis*(h*sc + sh), BN finalize fused (convergent barriers) ----
__global__ void __launch_bounds__(256) k_y2(const float* __restrict__ h,
                                            const float* __restrict__ partial,
                                            const float* __restrict__ gamma,
                                            const float* __restrict__ beta,
                                            const float* __restrict__ dis,
                                            unsigned short* __restrict__ y2b) {
  __shared__ float raw[32];
  __shared__ float scs[16], shs[16];
  int j = threadIdx.x;
  if (j < 32) {
    float a = 0.f;
    for (int b = 0; b < NSTAT; b++) a += partial[b * 32 + j];
    raw[j] = a;
  }
  __syncthreads();
  if (j < 16) {
    float mean = raw[j] * (1.0f / NN);
    float var = raw[16 + j] * (1.0f / NN) - mean * mean;
    float inv = rsqrtf(var + EPSV);
    float sc = gamma[j] * inv;
    scs[j] = sc;
    shs[j] = beta[j] - mean * sc;
  }
  __syncthreads();
  int node = blockIdx.x * blockDim.x + j;
  if (node >= NN) return;
  float d = dis[node];
  const f32x4* hp = (const f32x4*)(h + (size_t)node * HD);
  const f32x4* scp = (const f32x4*)scs;
  const f32x4* shp = (const f32x4*)shs;
  f32x4 v0 = (hp[0] * scp[0] + shp[0]) * d;
  f32x4 v1 = (hp[1] * scp[1] + shp[1]) * d;
  f32x4 v2 = (hp[2] * scp[2] + shp[2]) * d;
  f32x4 v3 = (hp[3] * scp[3] + shp[3]) * d;
  short8 r0, r1;
  r0[0] = f2bf(v0.x); r0[1] = f2bf(v0.y); r0[2] = f2bf(v0.z); r0[3] = f2bf(v0.w);
  r0[4] = f2bf(v1.x); r0[5] = f2bf(v1.y); r0[6] = f2bf(v1.z); r0[7] = f2bf(v1.w);
  r1[0] = f2bf(v2.x); r1[1] = f2bf(v2.y); r1[2] = f2bf(v2.z); r1[3] = f2bf(v2.w);
  r1[4] = f2bf(v3.x); r1[5] = f2bf(v3.y); r1[6] = f2bf(v3.z); r1[7] = f2bf(v3.w);
  short8* yp = (short8*)(y2b + (size_t)node * HD);
  yp[0] = r0; yp[1] = r1;
}

// ---- gather layer 2 (wave per node, 16 slots x 4-deep, uint2 loads):
//      lane-per-class W2 + log_softmax ----
__global__ void __launch_bounds__(256) k_g2(const int* __restrict__ off,
                                            const int* __restrict__ offe,
                                            const int* __restrict__ srcs,
                                            const float* __restrict__ dis,
                                            const unsigned short* __restrict__ y2b,
                                            const float* __restrict__ W2,
                                            const float* __restrict__ b2,
                                            float* __restrict__ out) {
  int node = (blockIdx.x * blockDim.x + threadIdx.x) >> 6;
  if (node >= NN) return;
  int lane = threadIdx.x & 63;
  int cp = lane & 3;           // channel quad
  int g = lane >> 2;           // edge slot 0..15
  int start = off[node], end = offe[node];
  const uint2* y2q = (const uint2*)y2b;
  float a0 = 0.f, a1 = 0.f, a2 = 0.f, a3 = 0.f;
  int i = start + g;
  for (; i + 48 < end; i += 64) {
    int r0 = srcs[i];
    int r1 = srcs[i + 16];
    int r2 = srcs[i + 32];
    int r3 = srcs[i + 48];
    uint2 q0 = y2q[(size_t)r0 * 4 + cp];
    uint2 q1 = y2q[(size_t)r1 * 4 + cp];
    uint2 q2 = y2q[(size_t)r2 * 4 + cp];
    uint2 q3 = y2q[(size_t)r3 * 4 + cp];
    float2 pa, pb;
    pa = bfp2f(q0.x); pb = bfp2f(q0.y); a0 += pa.x; a1 += pa.y; a2 += pb.x; a3 += pb.y;
    pa = bfp2f(q1.x); pb = bfp2f(q1.y); a0 += pa.x; a1 += pa.y; a2 += pb.x; a3 += pb.y;
    pa = bfp2f(q2.x); pb = bfp2f(q2.y); a0 += pa.x; a1 += pa.y; a2 += pb.x; a3 += pb.y;
    pa = bfp2f(q3.x); pb = bfp2f(q3.y); a0 += pa.x; a1 += pa.y; a2 += pb.x; a3 += pb.y;
  }
  for (; i < end; i += 16) {
    uint2 q = y2q[(size_t)srcs[i] * 4 + cp];
    float2 pa = bfp2f(q.x), pb = bfp2f(q.y);
    a0 += pa.x; a1 += pa.y; a2 += pb.x; a3 += pb.y;
  }
#pragma unroll
  for (int m = 4; m < 64; m <<= 1) {
    a0 += __shfl_xor(a0, m);
    a1 += __shfl_xor(a1, m);
    a2 += __shfl_xor(a2, m);
    a3 += __shfl_xor(a3, m);
  }
  // lane with cp=k holds channels 4k..4k+3 (replicated across g)
  float d = dis[node];
  uint2 qn = y2q[(size_t)node * 4 + cp];
  float2 pa = bfp2f(qn.x), pb = bfp2f(qn.y);
  float r0 = d * (pa.x + a0);
  float r1 = d * (pa.y + a1);
  float r2 = d * (pb.x + a2);
  float r3 = d * (pb.y + a3);
  int cls = lane;
  float z = (cls < CD) ? b2[cls] : 0.f;
#pragma unroll
  for (int k = 0; k < 4; k++) {
    float s0 = __shfl(r0, k);
    float s1 = __shfl(r1, k);
    float s2 = __shfl(r2, k);
    float s3 = __shfl(r3, k);
    if (cls < CD) {
      z += s0 * W2[(4 * k) * CD + cls];
      z += s1 * W2[(4 * k + 1) * CD + cls];
      z += s2 * W2[(4 * k + 2) * CD + cls];
      z += s3 * W2[(4 * k + 3) * CD + cls];
    }
  }
  float zz = (cls < CD) ? z : -1e30f;
#pragma unroll
  for (int m = 1; m < 64; m <<= 1) zz = fmaxf(zz, __shfl_xor(zz, m));
  float e = (cls < CD) ? __expf(z - zz) : 0.f;
#pragma unroll
  for (int m = 1; m < 64; m <<= 1) e += __shfl_xor(e, m);
  float l = __logf(e) + zz;
  if (cls < CD) out[(size_t)node * CD + cls] = z - l;
}

extern "C" void kernel_launch(void* const* d_in, const int* in_sizes, int n_in,
                              void* d_out, int out_size, void* d_ws, size_t ws_size,
                              hipStream_t stream) {
  const float* x     = (const float*)d_in[0];
  const int*   ei    = (const int*)d_in[1];
  const float* W1    = (const float*)d_in[2];
  const float* b1    = (const float*)d_in[3];
  const float* W2    = (const float*)d_in[4];
  const float* b2    = (const float*)d_in[5];
  const float* gamma = (const float*)d_in[6];
  const float* beta  = (const float*)d_in[7];
  float* out = (float*)d_out;

  float* ws = (float*)d_ws;
  float*          dis     = ws;                            // NN
  float*          partial = ws + NN;                       // NSTAT*32
  float*          xw      = partial + NSTAT * 32;          // NN*HD f32
  unsigned short* y1b     = (unsigned short*)(xw + (size_t)NN * HD);       // NN*HD bf16
  float*          h       = (float*)(y1b + (size_t)NN * HD);               // NN*HD f32
  unsigned short* y2b     = (unsigned short*)(h + (size_t)NN * HD);        // NN*HD bf16
  int*            off     = (int*)(y2b + (size_t)NN * HD); // NN
  int*            offe    = off + NN;                      // NN
  int*            srcs    = offe + NN;                     // NE
  int*            bkcur   = srcs + NE;                     // NBUK
  int*            gbase   = bkcur + NBUK;                  // 1
  unsigned*       part    = (unsigned*)(gbase + 1);        // NBUK*CAP

  const int nblk_n   = (NN + 255) / 256;
  const int nblk_gw  = (NN * 64 + 255) / 256;              // wave per node: 25000
  const int nblk_fat = NBLK_CNT + NBLK_MM;                 // 2345, %3 interleave

  k_init<<<1, 512, 0, stream>>>(bkcur, gbase);
  k_fat<<<nblk_fat, 256, 0, stream>>>(ei, bkcur, part, x, W1, xw);
  k_bucket<<<NBUK, 1024, 0, stream>>>(bkcur, part, xw, gbase, off, offe, dis, y1b, srcs);
  k_g1<<<nblk_gw, 256, 0, stream>>>(off, offe, srcs, dis, y1b, b1, h);
  k_stats<<<NSTAT, 256, 0, stream>>>(h, partial);
  k_y2<<<nblk_n, 256, 0, stream>>>(h, partial, gamma, beta, dis, y2b);
  k_g2<<<nblk_gw, 256, 0, stream>>>(off, offe, srcs, dis, y2b, W2, b2, out);
}